// Round 1
// baseline (911.838 us; speedup 1.0000x reference)
//
#include <hip/hip_runtime.h>
#include <cstdint>

#define T_STEPS 128
#define BATCH   1024
#define D_INPUT 96
#define H_DIM   128
#define NWIN    163   // 121 full 7-frame windows + 6 prefix partials + 36 clipped partials
#define BD      (BATCH * D_INPUT)   // 98304 floats per time frame

// (t, s) -> widx, or -1 when the reference window is empty (cur1 == +0)
__device__ __forceinline__ int widx_for(int t, int s) {
    if (t >= 49) return t - 49 + 7 * s;                 // slide regime: full windows
    if (s == 0)  return 121 + min(5, t);                // [0, min(5,t)]
    const int st = 7 * s - 1;
    if (t < st) return -1;
    const int len = min(7, t - st + 1);
    return (len == 7) ? st : (127 + (s - 1) * 6 + (len - 1));
}

// XOR swizzle keeping even/odd float2 pairs adjacent and 8B-aligned
__device__ __forceinline__ int swz_idx(int row, int col) {
    return (row << 7) | (col ^ ((row & 63) << 1));
}

// ---------------------------------------------------------------------------
// kT: Win (128x96) -> WinT (96x128), one-shot 48 KB transpose so kA1's weight
// staging is a coalesced read + conflict-free swizzled LDS write.
// ---------------------------------------------------------------------------
__global__ __launch_bounds__(256) void kT_wint(const float* __restrict__ Win,
                                               float* __restrict__ WinT) {
    const int e = blockIdx.x * 256 + threadIdx.x;       // < 128*96
    const int h = e / D_INPUT, d = e % D_INPUT;
    WinT[d * H_DIM + h] = Win[e];
}

// ---------------------------------------------------------------------------
// kA0: one streaming pass over x. Thread <-> (b,d); 7-frame ring in registers
// (t-loop fully unrolled -> all ring indices compile-time -> no scratch).
// Emits every window sum with the EXACT ascending-frame __fadd_rn chain the
// validated win_decode windows used. x read once (50 MB), WS written once
// (64 MB) -> pure HBM streaming instead of 390 MB of per-block L3 re-reads.
//   full window w (widx=w, 0..120): frames w..w+6, completes at t=w+6
//   s0 prefix (widx=121+t, t=0..5): frames 0..t
//   grow partial s in [1,6], len in [1,6] (widx=127+(s-1)*6+(len-1)):
//     frames (7s-1)..(7s-2+len), completes at t=7s-2+len
// ---------------------------------------------------------------------------
__global__ __launch_bounds__(256) void kA0_winsum(const float* __restrict__ x,
                                                  float* __restrict__ WS) {
    const int flat = blockIdx.x * 256 + threadIdx.x;    // b*96 + d
    float* wsp = WS + flat;
    float r[7];
#pragma unroll
    for (int t = 0; t < T_STEPS; ++t) {
        r[t % 7] = x[(size_t)t * BD + flat];
        if (t <= 5) {                                   // s0 prefix, len = t+1
            float s = r[0];
#pragma unroll
            for (int k = 1; k <= t; ++k) s = __fadd_rn(s, r[k % 7]);
            wsp[(size_t)(121 + t) * BD] = s;
        }
        if (t >= 6 && t <= 126) {                       // full window w = t-6
            const int w = t - 6;
            float s = r[w % 7];
#pragma unroll
            for (int k = 1; k < 7; ++k) s = __fadd_rn(s, r[(w + k) % 7]);
            wsp[(size_t)w * BD] = s;
        }
        if (t >= 6 && t <= 46) {                        // grow partial (<=1 per t)
            const int sv = (t + 1) / 7;
            if (sv >= 1 && 7 * sv >= t - 4 && 7 * sv <= t + 1) {
                const int start = 7 * sv - 1;
                const int len = t - start + 1;          // 1..6 by construction
                float s = r[start % 7];
#pragma unroll
                for (int k = 1; k < len; ++k) s = __fadd_rn(s, r[(start + k) % 7]);
                wsp[(size_t)(127 + (sv - 1) * 6 + (len - 1)) * BD] = s;
            }
        }
    }
}

// ---------------------------------------------------------------------------
// kA1: CUR1[widx][b][h] = seqFMA_{d}( WS[widx][b][d], Win[h][d] ) — compute
// loop and output layout byte-identical to the validated kernel (ascending-d
// single-acc fmaf), so CUR1 is bit-identical and kB sees identical inputs.
// Changes vs previous round: window sums come from WS (12 KB coalesced tile
// load) instead of len x 12 KB strided x re-reads; weights staged from WinT
// via float2 (coalesced read, conflict-free swizzled write — the old
// transposing write was ~32-way bank-conflicted per block x 5216 blocks).
// ---------------------------------------------------------------------------
__global__ __launch_bounds__(256) void kA_wincur(const float* __restrict__ WS,
                                                 const float* __restrict__ WinT,
                                                 float* __restrict__ CUR1) {
    __shared__ float xs[D_INPUT * 32];                  // xs[d*32 + bq], 12 KB
    __shared__ float wT[D_INPUT * H_DIM];               // 48 KB, wT[swz_idx(d,h)]
    const int widx = blockIdx.x;
    const int b0   = blockIdx.y * 32;
    const int tid  = threadIdx.x;

    // stage WinT: float2 coalesced reads; swz col = (2*h2)^even -> pair stays
    // adjacent & 8B-aligned; consecutive lanes step h2 -> distinct banks.
    {
        const float2* WinT2 = (const float2*)WinT;
        for (int e2 = tid; e2 < D_INPUT * (H_DIM / 2); e2 += 256) {
            const int d = e2 >> 6, h2 = e2 & 63;
            *(float2*)&wT[swz_idx(d, h2 << 1)] = WinT2[e2];
        }
    }
    // stage WS tile (coalesced 12 KB read; transposed LDS write is only 12
    // wave-writes/thread-iter -> conflict cost negligible)
    for (int e = tid; e < D_INPUT * 32; e += 256) {
        const int d = e % D_INPUT, bq = e / D_INPUT;
        xs[d * 32 + bq] = WS[(size_t)widx * BD + (size_t)(b0 + bq) * D_INPUT + d];
    }
    __syncthreads();

    const int hp = tid & 63, g = tid >> 6;              // h-pair; wave -> b-octet
    const int h0 = hp << 1;
    float acc[8][2];
#pragma unroll
    for (int r = 0; r < 8; ++r) { acc[r][0] = 0.f; acc[r][1] = 0.f; }

#pragma unroll 6
    for (int d = 0; d < D_INPUT; ++d) {                 // ascending d, one acc each (exact)
        const float2 wp  = *(const float2*)&wT[swz_idx(d, h0)];      // ds_read_b64
        const float4 xv0 = *(const float4*)&xs[d * 32 + g * 8];      // broadcast b128
        const float4 xv1 = *(const float4*)&xs[d * 32 + g * 8 + 4];
        const float xv[8] = {xv0.x,xv0.y,xv0.z,xv0.w, xv1.x,xv1.y,xv1.z,xv1.w};
#pragma unroll
        for (int r = 0; r < 8; ++r) {
            acc[r][0] = __fmaf_rn(xv[r], wp.x, acc[r][0]);
            acc[r][1] = __fmaf_rn(xv[r], wp.y, acc[r][1]);
        }
    }
    float* op = CUR1 + ((size_t)widx * BATCH + b0 + g * 8) * H_DIM + h0;
#pragma unroll
    for (int r = 0; r < 8; ++r) {
        float2 o; o.x = acc[r][0]; o.y = acc[r][1];
        *(float2*)(op + (size_t)r * H_DIM) = o;
    }
}

// ---------------------------------------------------------------------------
// kB: 7 SNN steps, SIXTEEN (t,b) pairs per wave (per j: 2 b64 + 8 broadcast
// b128 ≈ 52 LDS-cyc vs 64 fma = 128 VALU-cyc — VALU-dominant, ILP hides LDS
// latency at 2 waves/SIMD). 8 waves/block share the 64 KB swizzled W_h0
// table; per-wave 8 KB sf strip publishes spike {0,1} floats with chunk
// swizzle c^(lane&7) (round 7's writes were 16/32-way bank-conflicted).
// cur1 prefetch for s+1 reuses the dead c1 registers. Bit-exact: same {0,1}
// values, same ascending-h single-accumulator fma chain; membranes
// rn(rn(0.9*m)+c) with select-0 reset. Linear W_out/mem_out tail relaxed.
// __launch_bounds__(512,2): VGPR cap 256 (spill guard, round-4 lesson).
// UNCHANGED this round.
// ---------------------------------------------------------------------------
__global__ __launch_bounds__(512, 2) void kB_snn(const float* __restrict__ CUR1,
                                                 const float* __restrict__ Wh0,
                                                 const float* __restrict__ Wout,
                                                 const float* __restrict__ vxp,
                                                 const float* __restrict__ vyp,
                                                 float* __restrict__ out) {
    __shared__ float lw[H_DIM * H_DIM];                 // 64 KB, lw[swz_idx(h,i)]
    __shared__ float sf[8][64 * 32];                    // 64 KB, per-wave spike floats
    const int tid = threadIdx.x;
    for (int e = tid; e < H_DIM * H_DIM; e += 512) {
        const int i = e >> 7, h = e & 127;              // Wh0 flat = i*128 + h
        lw[swz_idx(h, i)] = Wh0[e];
    }
    __syncthreads();

    const int w = tid >> 6, lane = tid & 63;
    const int t  = blockIdx.y;
    const int i0 = lane << 1;
    float* sfw = sf[w];
    const int lbase = lane * 32;                        // this lane's publish strip
    const float wex = Wout[i0],     wey = Wout[H_DIM + i0];
    const float wox = Wout[i0 + 1], woy = Wout[H_DIM + i0 + 1];
    const float vx = vxp[0], vy = vyp[0];
    const int b0 = (blockIdx.x << 7) + (w << 4);        // 16 consecutive b per wave

    float m1a[16], m1b[16], m2a[16], m2b[16], poa[16], pob[16];
    float c1a[16], c1b[16];
    bool  s1a[16], s1b[16], s2a[16], s2b[16];
#pragma unroll
    for (int k = 0; k < 16; ++k) {
        m1a[k]=0.f; m1b[k]=0.f; m2a[k]=0.f; m2b[k]=0.f; poa[k]=0.f; pob[k]=0.f;
        s1a[k]=false; s1b[k]=false; s2a[k]=false; s2b[k]=false;
    }

    // load cur1 for s = 0
    {
        const int wi = widx_for(t, 0);
#pragma unroll
        for (int k = 0; k < 16; ++k) {
            c1a[k] = 0.f; c1b[k] = 0.f;
            if (wi >= 0) {
                const float2 v = *(const float2*)
                    &CUR1[((size_t)wi * BATCH + b0 + k) * H_DIM + i0];
                c1a[k] = v.x; c1b[k] = v.y;
            }
        }
    }

#pragma unroll 1
    for (int s = 0; s < 7; ++s) {
        // ---- mem1 update + spike floats (exact), publish to sf -------------
        float sev[16], sov[16];
#pragma unroll
        for (int k = 0; k < 16; ++k) {
            m1a[k] = s1a[k] ? 0.f : __fadd_rn(__fmul_rn(0.9f, m1a[k]), c1a[k]);
            m1b[k] = s1b[k] ? 0.f : __fadd_rn(__fmul_rn(0.9f, m1b[k]), c1b[k]);
            s1a[k] = m1a[k] > 0.5f; s1b[k] = m1b[k] > 0.5f;
            sev[k] = s1a[k] ? 1.0f : 0.0f;              // v_cndmask, once per step
            sov[k] = s1b[k] ? 1.0f : 0.0f;
        }
        // chunks 0..3 = se[0..15], 4..7 = so[0..15]; chunk swizzled by lane&7
#pragma unroll
        for (int c = 0; c < 4; ++c) {
            float4 v;
            v.x = sev[c*4]; v.y = sev[c*4+1]; v.z = sev[c*4+2]; v.w = sev[c*4+3];
            *(float4*)&sfw[lbase + ((c     ^ (lane & 7)) << 2)] = v;
            v.x = sov[c*4]; v.y = sov[c*4+1]; v.z = sov[c*4+2]; v.w = sov[c*4+3];
            *(float4*)&sfw[lbase + (((c+4) ^ (lane & 7)) << 2)] = v;
        }

        // ---- prefetch next step's cur1 into the now-dead c1 registers ------
        const int win = (s < 6) ? widx_for(t, s + 1) : -1;
#pragma unroll
        for (int k = 0; k < 16; ++k) {
            c1a[k] = 0.f; c1b[k] = 0.f;
            if (win >= 0) {
                const float2 v = *(const float2*)
                    &CUR1[((size_t)win * BATCH + b0 + k) * H_DIM + i0];
                c1a[k] = v.x; c1b[k] = v.y;
            }
        }

        // ---- dense cur2: ascending h, fma with broadcast spike floats ------
        float c2a[16], c2b[16];
#pragma unroll
        for (int k = 0; k < 16; ++k) { c2a[k] = 0.f; c2b[k] = 0.f; }
#pragma unroll 8
        for (int j = 0; j < 64; ++j) {
            const float2 we = *(const float2*)&lw[swz_idx(2*j,     i0)]; // per-lane b64
            const float2 wo = *(const float2*)&lw[swz_idx(2*j + 1, i0)];
            const int jb = j * 32, jx = (j & 7) << 2;                    // chunk swizzle
            const float4 e0 = *(const float4*)&sfw[jb + ((0  << 2) ^ jx)];
            const float4 e1 = *(const float4*)&sfw[jb + ((1  << 2) ^ jx)];
            const float4 e2 = *(const float4*)&sfw[jb + ((2  << 2) ^ jx)];
            const float4 e3 = *(const float4*)&sfw[jb + ((3  << 2) ^ jx)];
            const float4 o0 = *(const float4*)&sfw[jb + ((4  << 2) ^ jx)];
            const float4 o1 = *(const float4*)&sfw[jb + ((5  << 2) ^ jx)];
            const float4 o2 = *(const float4*)&sfw[jb + ((6  << 2) ^ jx)];
            const float4 o3 = *(const float4*)&sfw[jb + ((7  << 2) ^ jx)];
            const float se[16] = {e0.x,e0.y,e0.z,e0.w, e1.x,e1.y,e1.z,e1.w,
                                  e2.x,e2.y,e2.z,e2.w, e3.x,e3.y,e3.z,e3.w};
            const float so[16] = {o0.x,o0.y,o0.z,o0.w, o1.x,o1.y,o1.z,o1.w,
                                  o2.x,o2.y,o2.z,o2.w, o3.x,o3.y,o3.z,o3.w};
#pragma unroll
            for (int k = 0; k < 16; ++k) {
                c2a[k] = __fmaf_rn(se[k], we.x, c2a[k]);   // h = 2j
                c2b[k] = __fmaf_rn(se[k], we.y, c2b[k]);
                c2a[k] = __fmaf_rn(so[k], wo.x, c2a[k]);   // h = 2j+1
                c2b[k] = __fmaf_rn(so[k], wo.y, c2b[k]);
            }
        }

        // ---- mem2 + spikes (exact) and linear output tail (relaxed) --------
#pragma unroll
        for (int k = 0; k < 16; ++k) {
            m2a[k] = s2a[k] ? 0.f : __fadd_rn(__fmul_rn(0.9f, m2a[k]), c2a[k]);
            m2b[k] = s2b[k] ? 0.f : __fadd_rn(__fmul_rn(0.9f, m2b[k]), c2b[k]);
            s2a[k] = m2a[k] > 0.5f; s2b[k] = m2b[k] > 0.5f;
            const float p0 = (s2a[k] ? wex : 0.f) + (s2b[k] ? wox : 0.f);
            const float p1 = (s2a[k] ? wey : 0.f) + (s2b[k] ? woy : 0.f);
            poa[k] = __fmaf_rn(0.9f, poa[k], p0);       // mem_out is linear: order-safe
            pob[k] = __fmaf_rn(0.9f, pob[k], p1);
        }
    }

    // ---- reduce per-lane output partials, write -----------------------------
#pragma unroll
    for (int k = 0; k < 16; ++k) {
        float r0 = poa[k], r1 = pob[k];
#pragma unroll
        for (int off = 32; off > 0; off >>= 1) {
            r0 += __shfl_xor(r0, off);
            r1 += __shfl_xor(r1, off);
        }
        if (lane == 0) {
            float2 o;
            o.x = __fmul_rn(r0, vx);
            o.y = __fmul_rn(r1, vy);
            *(float2*)(out + ((size_t)t * BATCH + b0 + k) * 2) = o;
        }
    }
}

// ---------------------------------------------------------------------------
extern "C" void kernel_launch(void* const* d_in, const int* in_sizes, int n_in,
                              void* d_out, int out_size, void* d_ws, size_t ws_size,
                              hipStream_t stream) {
    const float* x    = (const float*)d_in[0];   // (128,1024,96)
    const float* Win  = (const float*)d_in[1];   // (128,96)
    const float* Wh0  = (const float*)d_in[2];   // (128,128)
    const float* Wout = (const float*)d_in[3];   // (2,128)
    const float* vx   = (const float*)d_in[4];   // (1,)
    const float* vy   = (const float*)d_in[5];   // (1,)
    float* out  = (float*)d_out;                 // (128,1024,2)

    // workspace layout: CUR1 (85.5 MB) | WS (64.1 MB) | WinT (48 KB) ≈ 150 MB
    float* CUR1 = (float*)d_ws;
    float* WS   = CUR1 + (size_t)NWIN * BATCH * H_DIM;
    float* WinT = WS   + (size_t)NWIN * BATCH * D_INPUT;

    kT_wint  <<<dim3((H_DIM * D_INPUT) / 256), dim3(256), 0, stream>>>(Win, WinT);
    kA0_winsum<<<dim3(BD / 256),               dim3(256), 0, stream>>>(x, WS);
    kA_wincur<<<dim3(NWIN, BATCH / 32),        dim3(256), 0, stream>>>(WS, WinT, CUR1);
    kB_snn   <<<dim3(BATCH / 128, T_STEPS),    dim3(512), 0, stream>>>(CUR1, Wh0, Wout, vx, vy, out);
}